// Round 1
// 310.103 us; speedup vs baseline: 1.0144x; 1.0144x over previous
//
#include <hip/hip_runtime.h>
#include <stdint.h>

#define DI static __device__ __forceinline__

constexpr int NTOK = 9216;   // 96*96 feat tokens per batch
constexpr float ATT_SCALE = 0.125f;

typedef short bf16x8 __attribute__((ext_vector_type(8)));
typedef float f32x4  __attribute__((ext_vector_type(4)));

DI f32x4 mfma16(bf16x8 a, bf16x8 b, f32x4 c) {
  return __builtin_amdgcn_mfma_f32_16x16x32_bf16(a, b, c, 0, 0, 0);
}

DI float lo2f(uint32_t u) { union { uint32_t i; float f; } v; v.i = u << 16; return v.f; }
DI float hi2f(uint32_t u) { union { uint32_t i; float f; } v; v.i = u & 0xffff0000u; return v.f; }
DI float b2f(uint16_t u) { union { uint32_t i; float f; } v; v.i = ((uint32_t)u) << 16; return v.f; }
DI uint16_t f2b(float f) {
  union { float f; uint32_t i; } v; v.f = f;
  uint32_t r = (v.i + 0x7fffu + ((v.i >> 16) & 1u)) >> 16;
  return (uint16_t)r;
}

// ---- dtype-generic element access (DT: 1 = bf16 storage, 0 = fp32 storage) --
template<int DT> DI float ld1(const void* p, size_t off) {
  if constexpr (DT) return b2f(((const uint16_t*)p)[off]);
  else              return ((const float*)p)[off];
}
template<int DT> DI void st1(void* p, size_t off, float v) {
  if constexpr (DT) ((uint16_t*)p)[off] = f2b(v);
  else              ((float*)p)[off] = v;
}

// ---------------------------------------------------------------------------
// dtype detector (wave-parallel): flag=1 -> bf16 inputs, 0 -> fp32 inputs
// ---------------------------------------------------------------------------
__global__ void detect_dtype(const uint32_t* __restrict__ w, int* __restrict__ flag) {
  const int l = threadIdx.x;   // 64 lanes
  int cl = 0;
  #pragma unroll
  for (int i = 0; i < 4; ++i) {
    const float b = b2f((uint16_t)(w[l + i * 64] & 0xffffu));
    const float ab = fabsf(b);
    cl += (ab > 1e-4f && ab < 0.5f) ? 1 : 0;
  }
  cl += __shfl_xor(cl, 1);  cl += __shfl_xor(cl, 2);  cl += __shfl_xor(cl, 4);
  cl += __shfl_xor(cl, 8);  cl += __shfl_xor(cl, 16); cl += __shfl_xor(cl, 32);
  if (l == 0) flag[0] = (cl >= 128) ? 1 : 0;
}

// ---------------------------------------------------------------------------
// Weight prep (bf16, MFMA-ready). WqvP now stored in NATURAL k-order:
// the old k-slot permute only existed to bank-spread gemm0's scalar B-gather,
// which is gone (B is now read as ds_read_b128 from a transposed LDS tile).
// ---------------------------------------------------------------------------
template<int DT>
DI void prep_w_body(const void* __restrict__ Wfqv, const void* __restrict__ Wfo,
                    uint16_t* __restrict__ WqvP, uint16_t* __restrict__ WfoP)
{
  const int r = blockIdx.x, c = threadIdx.x;
  if (r < 512) {
    const int sel = r >> 8, within = r & 255;
    const int h = within >> 6, d = within & 63;
    const int src = sel * 256 + d * 4 + h;
    WqvP[(size_t)r * 256 + c] = f2b(ld1<DT>(Wfqv, (size_t)src * 256 + c));
  } else {
    const int ro = r - 512;
    WfoP[(size_t)ro * 256 + c] =
        f2b(ld1<DT>(Wfo, (size_t)ro * 256 + (c & 63) * 4 + (c >> 6)));
  }
}
__global__ __launch_bounds__(256) void prep_w(
    const void* Wfqv, const void* Wfo, uint16_t* WqvP, uint16_t* WfoP,
    const int* __restrict__ flag)
{
  if (flag[0]) prep_w_body<1>(Wfqv, Wfo, WqvP, WfoP);
  else         prep_w_body<0>(Wfqv, Wfo, WqvP, WfoP);
}

// ---------------------------------------------------------------------------
// GEMM0 (QV projection), MFMA. Grid (144 n-slabs, 4 batch), 256 thr.
// One block = 64 tokens x ALL 512 output channels (wave w = head w), so
// feat is fetched exactly once (was 4x: one pass per head).
// X tile (256k x 64n) staged ONCE, transposed to Xs[n][k] (pitch 280,
// conflict-free for b128 reads) -> zero barriers in the k-loop and the
// B-fragment is a single ds_read_b128 (was 8 scalar ds_read_u16).
// Outputs: FQ token-major [bh][n][64d]; FVt tiled [bh][it(288)][64d][32i].
// ---------------------------------------------------------------------------
constexpr int P0 = 280;   // gemm0 LDS token-row pitch (elems); 560B rows,
                          // bank start (12l+4q)%32 -> uniform 8 acc/bank

template<int DT>
DI void gemm0_body(uint16_t* Xs, const uint16_t* __restrict__ WqvP,
                   const void* __restrict__ X,
                   uint16_t* __restrict__ FQ, uint16_t* __restrict__ FVt)
{
  const int tid = threadIdx.x;
  const int w = tid >> 6, lane = tid & 63;
  const int l = lane & 15, quad = lane >> 4;
  const int n0 = blockIdx.x * 64;
  const int bb = blockIdx.y;
  const size_t bh = (size_t)bb * 4 + w;    // wave w handles head w

  // ---- stage X[256k][64n] -> Xs[n][k] bf16, one shot
  {
    const int nh = (tid & 1) * 32;
    #pragma unroll
    for (int p = 0; p < 2; ++p) {
      const int c = p * 128 + (tid >> 1);
      const size_t g = ((size_t)bb * 256 + c) * NTOK + n0 + nh;
      if constexpr (DT) {
        #pragma unroll
        for (int u = 0; u < 4; ++u) {
          const uint4 v = *(const uint4*)((const uint16_t*)X + g + u * 8);
          const uint16_t* pk = (const uint16_t*)&v;
          #pragma unroll
          for (int j = 0; j < 8; ++j)
            Xs[(size_t)(nh + u * 8 + j) * P0 + c] = pk[j];
        }
      } else {
        #pragma unroll
        for (int u = 0; u < 8; ++u) {
          const float4 v = *(const float4*)((const float*)X + g + u * 4);
          Xs[(size_t)(nh + u * 4 + 0) * P0 + c] = f2b(v.x);
          Xs[(size_t)(nh + u * 4 + 1) * P0 + c] = f2b(v.y);
          Xs[(size_t)(nh + u * 4 + 2) * P0 + c] = f2b(v.z);
          Xs[(size_t)(nh + u * 4 + 3) * P0 + c] = f2b(v.w);
        }
      }
    }
  }
  __syncthreads();

  f32x4 acc[8][4];
  #pragma unroll
  for (int a = 0; a < 8; ++a)
    #pragma unroll
    for (int b = 0; b < 4; ++b) { acc[a][b].x = 0.f; acc[a][b].y = 0.f; acc[a][b].z = 0.f; acc[a][b].w = 0.f; }

  for (int ks = 0; ks < 8; ++ks) {
    bf16x8 af[8];
    #pragma unroll
    for (int mt = 0; mt < 8; ++mt) {
      const int arow = (mt >> 2) * 256 + w * 64 + (mt & 3) * 16 + l;
      af[mt] = *(const bf16x8*)(WqvP + (size_t)arow * 256 + ks * 32 + quad * 8);
    }
    #pragma unroll
    for (int nt = 0; nt < 4; ++nt) {
      const bf16x8 bv = *(const bf16x8*)(Xs + (size_t)(nt * 16 + l) * P0 + ks * 32 + quad * 8);
      #pragma unroll
      for (int mt = 0; mt < 8; ++mt)
        acc[mt][nt] = mfma16(af[mt], bv, acc[mt][nt]);
    }
  }
  #pragma unroll
  for (int mt = 0; mt < 8; ++mt)
    #pragma unroll
    for (int nt = 0; nt < 4; ++nt) {
      const int n = n0 + nt * 16 + l;
      if (mt < 4) {
        union { uint16_t h[4]; uint2 u; } pk;
        #pragma unroll
        for (int r = 0; r < 4; ++r) pk.h[r] = f2b(acc[mt][nt][r]);
        *(uint2*)(FQ + (bh * NTOK + n) * 64 + mt * 16 + quad * 4) = pk.u;
      } else {
        const int itile = n >> 5, io = n & 31;
        #pragma unroll
        for (int r = 0; r < 4; ++r)
          FVt[(((size_t)bh * 288 + itile) * 64 + (mt - 4) * 16 + quad * 4 + r) * 32 + io] =
              f2b(acc[mt][nt][r]);
      }
    }
}
__global__ __launch_bounds__(256) void gemm0_mfma(
    const uint16_t* WqvP, const void* X, uint16_t* FQ, uint16_t* FVt,
    const int* __restrict__ flag)
{
  __shared__ __align__(16) uint16_t Xs[64 * P0];
  if (flag[0]) gemm0_body<1>(Xs, WqvP, X, FQ, FVt);
  else         gemm0_body<0>(Xs, WqvP, X, FQ, FVt);
}

// ---------------------------------------------------------------------------
// GEMM1 (feat out projection), MFMA, LDS-free. Grid (36, 4 o-slabs, 4 b).
// ---------------------------------------------------------------------------
template<int DT>
DI void gemm1_body(const uint16_t* __restrict__ WfoP, const uint16_t* __restrict__ FO,
                   void* __restrict__ out)
{
  const int tid = threadIdx.x;
  const int w = tid >> 6, lane = tid & 63;
  const int l = lane & 15, quad = lane >> 4;
  const int n0 = blockIdx.x * 256;
  const int o0 = blockIdx.y * 64;
  const int bb = blockIdx.z;

  f32x4 acc[4][4];
  #pragma unroll
  for (int a = 0; a < 4; ++a)
    #pragma unroll
    for (int b = 0; b < 4; ++b) { acc[a][b].x = 0.f; acc[a][b].y = 0.f; acc[a][b].z = 0.f; acc[a][b].w = 0.f; }

  for (int ks = 0; ks < 8; ++ks) {
    const int h2 = ks >> 1;
    const int doff = (ks & 1) * 32 + quad * 8;
    bf16x8 af[4];
    #pragma unroll
    for (int mt = 0; mt < 4; ++mt)
      af[mt] = *(const bf16x8*)(WfoP + (size_t)(o0 + mt * 16 + l) * 256 + ks * 32 + quad * 8);
    #pragma unroll
    for (int nt = 0; nt < 4; ++nt) {
      const int n = n0 + w * 64 + nt * 16 + l;
      const bf16x8 bv = *(const bf16x8*)(FO + ((size_t)(bb * 4 + h2) * NTOK + n) * 64 + doff);
      #pragma unroll
      for (int mt = 0; mt < 4; ++mt)
        acc[mt][nt] = mfma16(af[mt], bv, acc[mt][nt]);
    }
  }
  #pragma unroll
  for (int mt = 0; mt < 4; ++mt)
    #pragma unroll
    for (int nt = 0; nt < 4; ++nt) {
      const int n = n0 + w * 64 + nt * 16 + l;
      #pragma unroll
      for (int r = 0; r < 4; ++r)
        st1<DT>(out, ((size_t)bb * 256 + o0 + mt * 16 + quad * 4 + r) * NTOK + n,
                acc[mt][nt][r]);
    }
}
__global__ __launch_bounds__(256) void gemm1_mfma(
    const uint16_t* WfoP, const uint16_t* FO, void* out,
    const int* __restrict__ flag)
{
  if (flag[0]) gemm1_body<1>(WfoP, FO, out);
  else         gemm1_body<0>(WfoP, FO, out);
}

// ---------------------------------------------------------------------------
// map QV projection (tiny): MQ[bh][m][d] token-major, MVT[bh][d][m] d-major
// ---------------------------------------------------------------------------
template<int DT>
DI void map_qv_body(const void* __restrict__ Wqv, const void* __restrict__ smap,
                    uint16_t* __restrict__ MQ, uint16_t* __restrict__ MVT)
{
  const int o = blockIdx.x, bb = blockIdx.y, m = threadIdx.x;
  float acc = 0.f;
  #pragma unroll 8
  for (int c = 0; c < 256; ++c)
    acc += ld1<DT>(Wqv, (size_t)o * 256 + c) *
           ld1<DT>(smap, (size_t)bb * 65536 + (size_t)c * 256 + m);
  const int oc = o & 255;
  const int h = oc & 3, d = oc >> 2;
  if (o < 256) MQ[(((size_t)bb * 4 + h) * 256 + m) * 64 + d] = f2b(acc);
  else         MVT[(((size_t)bb * 4 + h) * 64 + d) * 256 + m] = f2b(acc);
}
__global__ __launch_bounds__(256) void map_qv(
    const void* Wqv, const void* smap, uint16_t* MQ, uint16_t* MVT,
    const int* __restrict__ flag)
{
  if (flag[0]) map_qv_body<1>(Wqv, smap, MQ, MVT);
  else         map_qv_body<0>(Wqv, smap, MQ, MVT);
}

// ---------------------------------------------------------------------------
// Fused bidirectional attention, MFMA 16x16x32 bf16.
// Grid (36, 16). Latency fixes this round:
//  - qa (FQ) double-buffered: t+1's fragments prefetched at top of iter t
//  - av (FVt) issued at top of the iteration, consumed in the column phase
//  - conflict-free LDS pitches: PJ 264->280 (row reads uniform 8 acc/bank),
//    PI 48->40 (col reads uniform). LDS 46.6 -> 43.5 KB, still 3 blocks/CU.
// ---------------------------------------------------------------------------
constexpr int PJ = 280;  // E[i][j] row pitch (560B rows, 16B-aligned)
constexpr int PI = 40;   // ET[j][i] row pitch (80B rows, 16B-aligned)
constexpr int PO = 72;   // Osh row pitch (144 B: 16B-aligned, bank-spread)
constexpr int NGRP = 36; // partial groups (= blocks) per bh

__global__ __launch_bounds__(256, 3) void attn_mfma(
    const uint16_t* __restrict__ FQ, const uint16_t* __restrict__ FVt,
    const uint16_t* __restrict__ MQ, const uint16_t* __restrict__ MVT,
    uint16_t* __restrict__ FO, uint16_t* __restrict__ P)
{
  __shared__ __align__(16) uint16_t Esh[32 * PJ];    // [i][j]
  __shared__ __align__(16) uint16_t ETsh[256 * PI];  // [j][i]
  __shared__ __align__(16) uint16_t Osh[32 * PO];    // [i][d] out-staging
  __shared__ float RS[4][32];
  const int tid = threadIdx.x;
  const int w = tid >> 6;
  const int lane = tid & 63;
  const int l = lane & 15, quad = lane >> 4;
  const int blk = blockIdx.x, bh = blockIdx.y;
  const uint16_t* FQh  = FQ  + (size_t)bh * NTOK * 64;
  const uint16_t* FVth = FVt + (size_t)bh * 288 * 64 * 32;
  const uint16_t* MQh  = MQ  + (size_t)bh * 256 * 64;
  const uint16_t* MVTh = MVT + (size_t)bh * 64 * 256;
  uint16_t* FOh = FO + (size_t)bh * NTOK * 64;

  f32x4 numacc[4][4];
  #pragma unroll
  for (int a = 0; a < 4; ++a)
    #pragma unroll
    for (int b = 0; b < 4; ++b) { numacc[a][b].x = 0.f; numacc[a][b].y = 0.f; numacc[a][b].z = 0.f; numacc[a][b].w = 0.f; }
  float csum[4] = {0.f, 0.f, 0.f, 0.f};

  // prefetch qa for t=0
  bf16x8 qa[2][2];
  {
    const int i0p = blk * 8 * 32;
    #pragma unroll
    for (int mt = 0; mt < 2; ++mt)
      #pragma unroll
      for (int kb = 0; kb < 2; ++kb)
        qa[mt][kb] = *(const bf16x8*)(FQh + (size_t)(i0p + mt * 16 + l) * 64 + kb * 32 + quad * 8);
  }

  for (int t = 0; t < 8; ++t) {
    const int it = blk * 8 + t;
    const int i0 = it * 32;

    // ---- issue this iter's column-phase FVt loads NOW (consumed much later)
    bf16x8 av[4];
    #pragma unroll
    for (int mt = 0; mt < 4; ++mt)
      av[mt] = *(const bf16x8*)(FVth + ((size_t)it * 64 + mt * 16 + l) * 32 + quad * 8);

    // ---- issue next iter's FQ loads (double-buffered qa)
    bf16x8 qn[2][2];
    {
      const int itn = blk * 8 + ((t + 1) & 7);
      const int i0n = itn * 32;
      #pragma unroll
      for (int mt = 0; mt < 2; ++mt)
        #pragma unroll
        for (int kb = 0; kb < 2; ++kb)
          qn[mt][kb] = *(const bf16x8*)(FQh + (size_t)(i0n + mt * 16 + l) * 64 + kb * 32 + quad * 8);
    }

    // ---- QK phase: e_ij into Esh [i][j] and ETsh [j][i]
    float rsum[2][4] = {{0.f,0.f,0.f,0.f},{0.f,0.f,0.f,0.f}};
    #pragma unroll
    for (int jt = 0; jt < 4; ++jt) {
      const int j0 = w * 64 + jt * 16;
      const bf16x8 kb0 = *(const bf16x8*)(MQh + (size_t)(j0 + l) * 64 + quad * 8);
      const bf16x8 kb1 = *(const bf16x8*)(MQh + (size_t)(j0 + l) * 64 + 32 + quad * 8);
      #pragma unroll
      for (int mt = 0; mt < 2; ++mt) {
        f32x4 acc = {0.f, 0.f, 0.f, 0.f};
        acc = mfma16(qa[mt][0], kb0, acc);
        acc = mfma16(qa[mt][1], kb1, acc);
        union { uint16_t h[4]; uint2 u; } pk;
        #pragma unroll
        for (int r = 0; r < 4; ++r) {
          const float e = __expf(acc[r] * ATT_SCALE);
          rsum[mt][r] += e;
          csum[jt] += e;
          pk.h[r] = f2b(e);
          Esh[(mt * 16 + quad * 4 + r) * PJ + j0 + l] = pk.h[r];
        }
        *(uint2*)(ETsh + (size_t)(j0 + l) * PI + mt * 16 + quad * 4) = pk.u;
      }
    }
    #pragma unroll
    for (int mt = 0; mt < 2; ++mt)
      #pragma unroll
      for (int r = 0; r < 4; ++r) {
        float v = rsum[mt][r];
        v += __shfl_xor(v, 1); v += __shfl_xor(v, 2);
        v += __shfl_xor(v, 4); v += __shfl_xor(v, 8);
        if (l == 0) RS[w][mt * 16 + quad * 4 + r] = v;
      }
    __syncthreads();

    // ---- row phase: feat_o^T[d][i] = MVT x E^T, normalized -> Osh
    {
      float rinv[2];
      #pragma unroll
      for (int nt = 0; nt < 2; ++nt) {
        const int i_ = nt * 16 + l;
        rinv[nt] = 1.f / (RS[0][i_] + RS[1][i_] + RS[2][i_] + RS[3][i_]);
      }
      f32x4 oacc[2];
      oacc[0].x=0.f;oacc[0].y=0.f;oacc[0].z=0.f;oacc[0].w=0.f;
      oacc[1]=oacc[0];
      #pragma unroll
      for (int ks = 0; ks < 8; ++ks) {
        const bf16x8 avr = *(const bf16x8*)(MVTh + (size_t)(w * 16 + l) * 256 + ks * 32 + quad * 8);
        #pragma unroll
        for (int nt = 0; nt < 2; ++nt) {
          const bf16x8 bv = *(const bf16x8*)(Esh + (size_t)(nt * 16 + l) * PJ + ks * 32 + quad * 8);
          oacc[nt] = mfma16(avr, bv, oacc[nt]);
        }
      }
      #pragma unroll
      for (int nt = 0; nt < 2; ++nt) {
        union { uint16_t h[4]; uint2 u; } pk;
        #pragma unroll
        for (int r = 0; r < 4; ++r) pk.h[r] = f2b(oacc[nt][r] * rinv[nt]);
        *(uint2*)(Osh + (nt * 16 + l) * PO + w * 16 + quad * 4) = pk.u;
      }
    }

    // ---- column phase: NUM^T[d][j] += FVt-tile x E (regs across tiles)
    #pragma unroll
    for (int mt = 0; mt < 4; ++mt) {
      #pragma unroll
      for (int nt2 = 0; nt2 < 4; ++nt2) {
        const bf16x8 bv = *(const bf16x8*)(ETsh + (size_t)(w * 64 + nt2 * 16 + l) * PI + quad * 8);
        numacc[mt][nt2] = mfma16(av[mt], bv, numacc[mt][nt2]);
      }
    }
    __syncthreads();

    // ---- FO write: full 128-B line per token (8 thr x uint4)
    {
      const int ti = tid >> 3, c = tid & 7;
      *(uint4*)(FOh + (size_t)(i0 + ti) * 64 + c * 8) =
          *(const uint4*)(Osh + ti * PO + c * 8);
    }

    // rotate prefetched qa (static copies, stays in registers)
    #pragma unroll
    for (int mt = 0; mt < 2; ++mt) {
      qa[mt][0] = qn[mt][0];
      qa[mt][1] = qn[mt][1];
    }
  }

  // ---- flush partials (plain bf16 stores, no atomics)
  uint16_t* Pb = P + ((size_t)bh * NGRP + blk) * 65 * 256;
  #pragma unroll
  for (int mt = 0; mt < 4; ++mt)
    #pragma unroll
    for (int nt2 = 0; nt2 < 4; ++nt2)
      #pragma unroll
      for (int r = 0; r < 4; ++r)
        Pb[(mt * 16 + quad * 4 + r) * 256 + w * 64 + nt2 * 16 + l] =
            f2b(numacc[mt][nt2][r]);
  #pragma unroll
  for (int jt = 0; jt < 4; ++jt) {
    float v = csum[jt];
    v += __shfl_xor(v, 16); v += __shfl_xor(v, 32);
    if (quad == 0) Pb[64 * 256 + w * 64 + jt * 16 + l] = f2b(v);
  }
}

// ---------------------------------------------------------------------------
// reduce partials -> map_o: MO[b][c=d*4+h][j] = sum_g NUM / sum_g CS
// ---------------------------------------------------------------------------
__global__ __launch_bounds__(256) void reduce_map(
    const uint16_t* __restrict__ P, uint16_t* __restrict__ MO)
{
  const int idx = blockIdx.x * 256 + threadIdx.x;   // 262144 total
  const int bh = idx >> 14;
  const int d = (idx >> 8) & 63;
  const int j = idx & 255;
  const size_t base = (size_t)bh * NGRP * 65 * 256;
  float num = 0.f, cs = 0.f;
  #pragma unroll 6
  for (int g = 0; g < NGRP; ++g) {
    num += b2f(P[base + ((size_t)g * 65 + d) * 256 + j]);
    cs  += b2f(P[base + ((size_t)g * 65 + 64) * 256 + j]);
  }
  const float v = num / cs;
  const int b = bh >> 2, h = bh & 3;
  MO[((size_t)b * 256 + (d * 4 + h)) * 256 + j] = f2b(v);
}

// ---------------------------------------------------------------------------
// map output projection (tiny)
// ---------------------------------------------------------------------------
template<int DT>
DI void map_out_body(const void* __restrict__ Wmo, const uint16_t* __restrict__ MO,
                     void* __restrict__ out)
{
  const int o = blockIdx.x, bb = blockIdx.y, m = threadIdx.x;
  float acc = 0.f;
  #pragma unroll 8
  for (int c = 0; c < 256; ++c)
    acc += ld1<DT>(Wmo, (size_t)o * 256 + c) *
           b2f(MO[((size_t)bb * 256 + c) * 256 + m]);
  const size_t MAP_OFS = (size_t)4 * 256 * NTOK;
  st1<DT>(out, MAP_OFS + ((size_t)bb * 256 + o) * 256 + m, acc);
}
__global__ __launch_bounds__(256) void map_out_k(
    const void* Wmo, const uint16_t* MO, void* out, const int* __restrict__ flag)
{
  if (flag[0]) map_out_body<1>(Wmo, MO, out);
  else         map_out_body<0>(Wmo, MO, out);
}

extern "C" void kernel_launch(void* const* d_in, const int* in_sizes, int n_in,
                              void* d_out, int out_size, void* d_ws, size_t ws_size,
                              hipStream_t stream) {
  (void)in_sizes; (void)n_in; (void)out_size; (void)ws_size;
  const void* feat = d_in[0];
  const void* smap = d_in[1];
  const void* Wfqv = d_in[2];
  const void* Wmqv = d_in[3];
  const void* Wfo  = d_in[4];
  const void* Wmo  = d_in[5];
  char* ws = (char*)d_ws;

  const size_t BIG = (size_t)16 * 64 * NTOK * 2;   // 18,874,368 B
  const size_t SML = (size_t)16 * 256 * 64 * 2;    //    524,288 B
  const size_t FQ_OFF  = 0;                         // FO aliases FQ (token-major)
  const size_t FVT_OFF = FQ_OFF + BIG;
  const size_t MQ_OFF  = FVT_OFF + BIG;
  const size_t MVT_OFF = MQ_OFF + SML;
  const size_t MO_OFF  = MVT_OFF + SML;
  const size_t WQP_OFF = MO_OFF + (size_t)4 * 256 * 256 * 2;
  const size_t WFP_OFF = WQP_OFF + (size_t)512 * 256 * 2;
  const size_t FLAG_OFF = WFP_OFF + (size_t)256 * 256 * 2;

  uint16_t* FQ   = (uint16_t*)(ws + FQ_OFF);
  uint16_t* FVt  = (uint16_t*)(ws + FVT_OFF);
  uint16_t* MQ   = (uint16_t*)(ws + MQ_OFF);
  uint16_t* MVT  = (uint16_t*)(ws + MVT_OFF);
  uint16_t* MO   = (uint16_t*)(ws + MO_OFF);
  uint16_t* WqvP = (uint16_t*)(ws + WQP_OFF);
  uint16_t* WfoP = (uint16_t*)(ws + WFP_OFF);
  int* FLAG   = (int*)(ws + FLAG_OFF);

  // partial buffer P (16 bh x 36 grp x 65 rows x 256 j, bf16 = 19.17 MB)
  // lives in d_out: consumed by reduce_map BEFORE gemm1/map_out overwrite it.
  uint16_t* P = (uint16_t*)d_out;

  detect_dtype<<<dim3(1), dim3(64), 0, stream>>>((const uint32_t*)Wfqv, FLAG);
  prep_w<<<dim3(768), 256, 0, stream>>>(Wfqv, Wfo, WqvP, WfoP, FLAG);
  gemm0_mfma<<<dim3(144, 4), 256, 0, stream>>>(WqvP, feat, FQ, FVt, FLAG);
  map_qv<<<dim3(512, 4), 256, 0, stream>>>(Wmqv, smap, MQ, MVT, FLAG);
  attn_mfma<<<dim3(NGRP, 16), 256, 0, stream>>>(FQ, FVt, MQ, MVT, FQ, P);
  reduce_map<<<dim3(1024), 256, 0, stream>>>(P, MO);
  gemm1_mfma<<<dim3(36, 4, 4), 256, 0, stream>>>(WfoP, FQ, d_out, FLAG);
  map_out_k<<<dim3(256, 4), 256, 0, stream>>>(Wmo, MO, d_out, FLAG);
}

// Round 2
// 290.113 us; speedup vs baseline: 1.0843x; 1.0689x over previous
//
#include <hip/hip_runtime.h>
#include <stdint.h>

#define DI static __device__ __forceinline__

constexpr int NTOK = 9216;   // 96*96 feat tokens per batch
constexpr float ATT_SCALE = 0.125f;

typedef short bf16x8 __attribute__((ext_vector_type(8)));
typedef float f32x4  __attribute__((ext_vector_type(4)));

DI f32x4 mfma16(bf16x8 a, bf16x8 b, f32x4 c) {
  return __builtin_amdgcn_mfma_f32_16x16x32_bf16(a, b, c, 0, 0, 0);
}

DI float lo2f(uint32_t u) { union { uint32_t i; float f; } v; v.i = u << 16; return v.f; }
DI float hi2f(uint32_t u) { union { uint32_t i; float f; } v; v.i = u & 0xffff0000u; return v.f; }
DI float b2f(uint16_t u) { union { uint32_t i; float f; } v; v.i = ((uint32_t)u) << 16; return v.f; }
DI uint16_t f2b(float f) {
  union { float f; uint32_t i; } v; v.f = f;
  uint32_t r = (v.i + 0x7fffu + ((v.i >> 16) & 1u)) >> 16;
  return (uint16_t)r;
}

// ---- dtype-generic element access (DT: 1 = bf16 storage, 0 = fp32 storage) --
template<int DT> DI float ld1(const void* p, size_t off) {
  if constexpr (DT) return b2f(((const uint16_t*)p)[off]);
  else              return ((const float*)p)[off];
}
template<int DT> DI void st1(void* p, size_t off, float v) {
  if constexpr (DT) ((uint16_t*)p)[off] = f2b(v);
  else              ((float*)p)[off] = v;
}

// ---------------------------------------------------------------------------
// dtype detector (wave-parallel): flag=1 -> bf16 inputs, 0 -> fp32 inputs
// ---------------------------------------------------------------------------
__global__ void detect_dtype(const uint32_t* __restrict__ w, int* __restrict__ flag) {
  const int l = threadIdx.x;   // 64 lanes
  int cl = 0;
  #pragma unroll
  for (int i = 0; i < 4; ++i) {
    const float b = b2f((uint16_t)(w[l + i * 64] & 0xffffu));
    const float ab = fabsf(b);
    cl += (ab > 1e-4f && ab < 0.5f) ? 1 : 0;
  }
  cl += __shfl_xor(cl, 1);  cl += __shfl_xor(cl, 2);  cl += __shfl_xor(cl, 4);
  cl += __shfl_xor(cl, 8);  cl += __shfl_xor(cl, 16); cl += __shfl_xor(cl, 32);
  if (l == 0) flag[0] = (cl >= 128) ? 1 : 0;
}

// ---------------------------------------------------------------------------
// Weight prep (bf16, MFMA-ready), natural k-order.
// ---------------------------------------------------------------------------
template<int DT>
DI void prep_w_body(const void* __restrict__ Wfqv, const void* __restrict__ Wfo,
                    uint16_t* __restrict__ WqvP, uint16_t* __restrict__ WfoP)
{
  const int r = blockIdx.x, c = threadIdx.x;
  if (r < 512) {
    const int sel = r >> 8, within = r & 255;
    const int h = within >> 6, d = within & 63;
    const int src = sel * 256 + d * 4 + h;
    WqvP[(size_t)r * 256 + c] = f2b(ld1<DT>(Wfqv, (size_t)src * 256 + c));
  } else {
    const int ro = r - 512;
    WfoP[(size_t)ro * 256 + c] =
        f2b(ld1<DT>(Wfo, (size_t)ro * 256 + (c & 63) * 4 + (c >> 6)));
  }
}
__global__ __launch_bounds__(256) void prep_w(
    const void* Wfqv, const void* Wfo, uint16_t* WqvP, uint16_t* WfoP,
    const int* __restrict__ flag)
{
  if (flag[0]) prep_w_body<1>(Wfqv, Wfo, WqvP, WfoP);
  else         prep_w_body<0>(Wfqv, Wfo, WqvP, WfoP);
}

// ---------------------------------------------------------------------------
// GEMM0 (QV projection), MFMA. Grid (144 n-slabs, 4 batch), 256 thr.
// One block = 64 tokens x ALL 512 output channels (wave w = head w): feat
// fetched exactly once. X tile staged transposed once, barrier-free k-loop.
// ---------------------------------------------------------------------------
constexpr int P0 = 280;   // gemm0 LDS token-row pitch (elems)

template<int DT>
DI void gemm0_body(uint16_t* Xs, const uint16_t* __restrict__ WqvP,
                   const void* __restrict__ X,
                   uint16_t* __restrict__ FQ, uint16_t* __restrict__ FVt)
{
  const int tid = threadIdx.x;
  const int w = tid >> 6, lane = tid & 63;
  const int l = lane & 15, quad = lane >> 4;
  const int n0 = blockIdx.x * 64;
  const int bb = blockIdx.y;
  const size_t bh = (size_t)bb * 4 + w;    // wave w handles head w

  // ---- stage X[256k][64n] -> Xs[n][k] bf16, one shot
  {
    const int nh = (tid & 1) * 32;
    #pragma unroll
    for (int p = 0; p < 2; ++p) {
      const int c = p * 128 + (tid >> 1);
      const size_t g = ((size_t)bb * 256 + c) * NTOK + n0 + nh;
      if constexpr (DT) {
        #pragma unroll
        for (int u = 0; u < 4; ++u) {
          const uint4 v = *(const uint4*)((const uint16_t*)X + g + u * 8);
          const uint16_t* pk = (const uint16_t*)&v;
          #pragma unroll
          for (int j = 0; j < 8; ++j)
            Xs[(size_t)(nh + u * 8 + j) * P0 + c] = pk[j];
        }
      } else {
        #pragma unroll
        for (int u = 0; u < 8; ++u) {
          const float4 v = *(const float4*)((const float*)X + g + u * 4);
          Xs[(size_t)(nh + u * 4 + 0) * P0 + c] = f2b(v.x);
          Xs[(size_t)(nh + u * 4 + 1) * P0 + c] = f2b(v.y);
          Xs[(size_t)(nh + u * 4 + 2) * P0 + c] = f2b(v.z);
          Xs[(size_t)(nh + u * 4 + 3) * P0 + c] = f2b(v.w);
        }
      }
    }
  }
  __syncthreads();

  f32x4 acc[8][4];
  #pragma unroll
  for (int a = 0; a < 8; ++a)
    #pragma unroll
    for (int b = 0; b < 4; ++b) { acc[a][b].x = 0.f; acc[a][b].y = 0.f; acc[a][b].z = 0.f; acc[a][b].w = 0.f; }

  for (int ks = 0; ks < 8; ++ks) {
    bf16x8 af[8];
    #pragma unroll
    for (int mt = 0; mt < 8; ++mt) {
      const int arow = (mt >> 2) * 256 + w * 64 + (mt & 3) * 16 + l;
      af[mt] = *(const bf16x8*)(WqvP + (size_t)arow * 256 + ks * 32 + quad * 8);
    }
    #pragma unroll
    for (int nt = 0; nt < 4; ++nt) {
      const bf16x8 bv = *(const bf16x8*)(Xs + (size_t)(nt * 16 + l) * P0 + ks * 32 + quad * 8);
      #pragma unroll
      for (int mt = 0; mt < 8; ++mt)
        acc[mt][nt] = mfma16(af[mt], bv, acc[mt][nt]);
    }
  }
  #pragma unroll
  for (int mt = 0; mt < 8; ++mt)
    #pragma unroll
    for (int nt = 0; nt < 4; ++nt) {
      const int n = n0 + nt * 16 + l;
      if (mt < 4) {
        union { uint16_t h[4]; uint2 u; } pk;
        #pragma unroll
        for (int r = 0; r < 4; ++r) pk.h[r] = f2b(acc[mt][nt][r]);
        *(uint2*)(FQ + (bh * NTOK + n) * 64 + mt * 16 + quad * 4) = pk.u;
      } else {
        const int itile = n >> 5, io = n & 31;
        #pragma unroll
        for (int r = 0; r < 4; ++r)
          FVt[(((size_t)bh * 288 + itile) * 64 + (mt - 4) * 16 + quad * 4 + r) * 32 + io] =
              f2b(acc[mt][nt][r]);
      }
    }
}
__global__ __launch_bounds__(256) void gemm0_mfma(
    const uint16_t* WqvP, const void* X, uint16_t* FQ, uint16_t* FVt,
    const int* __restrict__ flag)
{
  __shared__ __align__(16) uint16_t Xs[64 * P0];
  if (flag[0]) gemm0_body<1>(Xs, WqvP, X, FQ, FVt);
  else         gemm0_body<0>(Xs, WqvP, X, FQ, FVt);
}

// ---------------------------------------------------------------------------
// GEMM1 (feat out projection), MFMA, LDS-free. Grid (36, 4 o-slabs, 4 b).
// ---------------------------------------------------------------------------
template<int DT>
DI void gemm1_body(const uint16_t* __restrict__ WfoP, const uint16_t* __restrict__ FO,
                   void* __restrict__ out)
{
  const int tid = threadIdx.x;
  const int w = tid >> 6, lane = tid & 63;
  const int l = lane & 15, quad = lane >> 4;
  const int n0 = blockIdx.x * 256;
  const int o0 = blockIdx.y * 64;
  const int bb = blockIdx.z;

  f32x4 acc[4][4];
  #pragma unroll
  for (int a = 0; a < 4; ++a)
    #pragma unroll
    for (int b = 0; b < 4; ++b) { acc[a][b].x = 0.f; acc[a][b].y = 0.f; acc[a][b].z = 0.f; acc[a][b].w = 0.f; }

  for (int ks = 0; ks < 8; ++ks) {
    const int h2 = ks >> 1;
    const int doff = (ks & 1) * 32 + quad * 8;
    bf16x8 af[4];
    #pragma unroll
    for (int mt = 0; mt < 4; ++mt)
      af[mt] = *(const bf16x8*)(WfoP + (size_t)(o0 + mt * 16 + l) * 256 + ks * 32 + quad * 8);
    #pragma unroll
    for (int nt = 0; nt < 4; ++nt) {
      const int n = n0 + w * 64 + nt * 16 + l;
      const bf16x8 bv = *(const bf16x8*)(FO + ((size_t)(bb * 4 + h2) * NTOK + n) * 64 + doff);
      #pragma unroll
      for (int mt = 0; mt < 4; ++mt)
        acc[mt][nt] = mfma16(af[mt], bv, acc[mt][nt]);
    }
  }
  #pragma unroll
  for (int mt = 0; mt < 4; ++mt)
    #pragma unroll
    for (int nt = 0; nt < 4; ++nt) {
      const int n = n0 + w * 64 + nt * 16 + l;
      #pragma unroll
      for (int r = 0; r < 4; ++r)
        st1<DT>(out, ((size_t)bb * 256 + o0 + mt * 16 + quad * 4 + r) * NTOK + n,
                acc[mt][nt][r]);
    }
}
__global__ __launch_bounds__(256) void gemm1_mfma(
    const uint16_t* WfoP, const uint16_t* FO, void* out,
    const int* __restrict__ flag)
{
  if (flag[0]) gemm1_body<1>(WfoP, FO, out);
  else         gemm1_body<0>(WfoP, FO, out);
}

// ---------------------------------------------------------------------------
// map QV projection (tiny): MQ[bh][m][d] token-major, MVT[bh][d][m] d-major
// ---------------------------------------------------------------------------
template<int DT>
DI void map_qv_body(const void* __restrict__ Wqv, const void* __restrict__ smap,
                    uint16_t* __restrict__ MQ, uint16_t* __restrict__ MVT)
{
  const int o = blockIdx.x, bb = blockIdx.y, m = threadIdx.x;
  float acc = 0.f;
  #pragma unroll 8
  for (int c = 0; c < 256; ++c)
    acc += ld1<DT>(Wqv, (size_t)o * 256 + c) *
           ld1<DT>(smap, (size_t)bb * 65536 + (size_t)c * 256 + m);
  const int oc = o & 255;
  const int h = oc & 3, d = oc >> 2;
  if (o < 256) MQ[(((size_t)bb * 4 + h) * 256 + m) * 64 + d] = f2b(acc);
  else         MVT[(((size_t)bb * 4 + h) * 64 + d) * 256 + m] = f2b(acc);
}
__global__ __launch_bounds__(256) void map_qv(
    const void* Wqv, const void* smap, uint16_t* MQ, uint16_t* MVT,
    const int* __restrict__ flag)
{
  if (flag[0]) map_qv_body<1>(Wqv, smap, MQ, MVT);
  else         map_qv_body<0>(Wqv, smap, MQ, MVT);
}

// ---------------------------------------------------------------------------
// Fused bidirectional attention, MFMA 16x16x32 bf16. Grid (36, 16).
// This round: MQ (kb) and MVT (avr) fragments are LOOP-INVARIANT across the
// 8 t-iterations -> hoisted into registers once per block. This removes
// ~290 MB of repeated L2/HBM reads (the round-1 FETCH=207MB regression) and
// 16 global loads per iteration. qn double-buffer dropped (VGPR headroom);
// av (FVt) issued between barrier and row phase so row-phase MFMAs cover
// its latency.
// ---------------------------------------------------------------------------
constexpr int PJ = 280;  // E[i][j] row pitch (560B rows, 16B-aligned)
constexpr int PI = 40;   // ET[j][i] row pitch (80B rows, 16B-aligned)
constexpr int PO = 72;   // Osh row pitch (144 B: 16B-aligned, bank-spread)
constexpr int NGRP = 36; // partial groups (= blocks) per bh

__global__ __launch_bounds__(256, 3) void attn_mfma(
    const uint16_t* __restrict__ FQ, const uint16_t* __restrict__ FVt,
    const uint16_t* __restrict__ MQ, const uint16_t* __restrict__ MVT,
    uint16_t* __restrict__ FO, uint16_t* __restrict__ P)
{
  __shared__ __align__(16) uint16_t Esh[32 * PJ];    // [i][j]
  __shared__ __align__(16) uint16_t ETsh[256 * PI];  // [j][i]
  __shared__ __align__(16) uint16_t Osh[32 * PO];    // [i][d] out-staging
  __shared__ float RS[4][32];
  const int tid = threadIdx.x;
  const int w = tid >> 6;
  const int lane = tid & 63;
  const int l = lane & 15, quad = lane >> 4;
  const int blk = blockIdx.x, bh = blockIdx.y;
  const uint16_t* FQh  = FQ  + (size_t)bh * NTOK * 64;
  const uint16_t* FVth = FVt + (size_t)bh * 288 * 64 * 32;
  const uint16_t* MQh  = MQ  + (size_t)bh * 256 * 64;
  const uint16_t* MVTh = MVT + (size_t)bh * 64 * 256;
  uint16_t* FOh = FO + (size_t)bh * NTOK * 64;

  // ---- hoisted loop-invariant operand fragments (live whole kernel) ----
  bf16x8 kb[4][2];   // MQ: wave w's 64 map-tokens, both k-halves (32 VGPR)
  #pragma unroll
  for (int jt = 0; jt < 4; ++jt) {
    const int j = w * 64 + jt * 16 + l;
    kb[jt][0] = *(const bf16x8*)(MQh + (size_t)j * 64 + quad * 8);
    kb[jt][1] = *(const bf16x8*)(MQh + (size_t)j * 64 + 32 + quad * 8);
  }
  bf16x8 avr[8];     // MVT: wave w's 16 d-rows, all 8 k-slices (32 VGPR)
  #pragma unroll
  for (int ks = 0; ks < 8; ++ks)
    avr[ks] = *(const bf16x8*)(MVTh + (size_t)(w * 16 + l) * 256 + ks * 32 + quad * 8);

  f32x4 numacc[4][4];
  #pragma unroll
  for (int a = 0; a < 4; ++a)
    #pragma unroll
    for (int b = 0; b < 4; ++b) { numacc[a][b].x = 0.f; numacc[a][b].y = 0.f; numacc[a][b].z = 0.f; numacc[a][b].w = 0.f; }
  float csum[4] = {0.f, 0.f, 0.f, 0.f};

  for (int t = 0; t < 8; ++t) {
    const int it = blk * 8 + t;
    const int i0 = it * 32;

    // ---- QK phase: e_ij into Esh [i][j] and ETsh [j][i]
    bf16x8 qa[2][2];
    #pragma unroll
    for (int mt = 0; mt < 2; ++mt)
      #pragma unroll
      for (int kbi = 0; kbi < 2; ++kbi)
        qa[mt][kbi] = *(const bf16x8*)(FQh + (size_t)(i0 + mt * 16 + l) * 64 + kbi * 32 + quad * 8);

    float rsum[2][4] = {{0.f,0.f,0.f,0.f},{0.f,0.f,0.f,0.f}};
    #pragma unroll
    for (int jt = 0; jt < 4; ++jt) {
      const int j0 = w * 64 + jt * 16;
      #pragma unroll
      for (int mt = 0; mt < 2; ++mt) {
        f32x4 acc = {0.f, 0.f, 0.f, 0.f};
        acc = mfma16(qa[mt][0], kb[jt][0], acc);
        acc = mfma16(qa[mt][1], kb[jt][1], acc);
        union { uint16_t h[4]; uint2 u; } pk;
        #pragma unroll
        for (int r = 0; r < 4; ++r) {
          const float e = __expf(acc[r] * ATT_SCALE);
          rsum[mt][r] += e;
          csum[jt] += e;
          pk.h[r] = f2b(e);
          Esh[(mt * 16 + quad * 4 + r) * PJ + j0 + l] = pk.h[r];
        }
        *(uint2*)(ETsh + (size_t)(j0 + l) * PI + mt * 16 + quad * 4) = pk.u;
      }
    }
    #pragma unroll
    for (int mt = 0; mt < 2; ++mt)
      #pragma unroll
      for (int r = 0; r < 4; ++r) {
        float v = rsum[mt][r];
        v += __shfl_xor(v, 1); v += __shfl_xor(v, 2);
        v += __shfl_xor(v, 4); v += __shfl_xor(v, 8);
        if (l == 0) RS[w][mt * 16 + quad * 4 + r] = v;
      }
    __syncthreads();

    // ---- issue column-phase FVt loads; row phase below covers their latency
    bf16x8 av[4];
    #pragma unroll
    for (int mt = 0; mt < 4; ++mt)
      av[mt] = *(const bf16x8*)(FVth + ((size_t)it * 64 + mt * 16 + l) * 32 + quad * 8);

    // ---- row phase: feat_o^T[d][i] = MVT x E^T, normalized -> Osh
    {
      float rinv[2];
      #pragma unroll
      for (int nt = 0; nt < 2; ++nt) {
        const int i_ = nt * 16 + l;
        rinv[nt] = 1.f / (RS[0][i_] + RS[1][i_] + RS[2][i_] + RS[3][i_]);
      }
      f32x4 oacc[2];
      oacc[0].x=0.f;oacc[0].y=0.f;oacc[0].z=0.f;oacc[0].w=0.f;
      oacc[1]=oacc[0];
      #pragma unroll
      for (int ks = 0; ks < 8; ++ks) {
        #pragma unroll
        for (int nt = 0; nt < 2; ++nt) {
          const bf16x8 bv = *(const bf16x8*)(Esh + (size_t)(nt * 16 + l) * PJ + ks * 32 + quad * 8);
          oacc[nt] = mfma16(avr[ks], bv, oacc[nt]);
        }
      }
      #pragma unroll
      for (int nt = 0; nt < 2; ++nt) {
        union { uint16_t h[4]; uint2 u; } pk;
        #pragma unroll
        for (int r = 0; r < 4; ++r) pk.h[r] = f2b(oacc[nt][r] * rinv[nt]);
        *(uint2*)(Osh + (nt * 16 + l) * PO + w * 16 + quad * 4) = pk.u;
      }
    }

    // ---- column phase: NUM^T[d][j] += FVt-tile x E (regs across tiles)
    #pragma unroll
    for (int mt = 0; mt < 4; ++mt) {
      #pragma unroll
      for (int nt2 = 0; nt2 < 4; ++nt2) {
        const bf16x8 bv = *(const bf16x8*)(ETsh + (size_t)(w * 64 + nt2 * 16 + l) * PI + quad * 8);
        numacc[mt][nt2] = mfma16(av[mt], bv, numacc[mt][nt2]);
      }
    }
    __syncthreads();

    // ---- FO write: full 128-B line per token (8 thr x uint4)
    {
      const int ti = tid >> 3, c = tid & 7;
      *(uint4*)(FOh + (size_t)(i0 + ti) * 64 + c * 8) =
          *(const uint4*)(Osh + ti * PO + c * 8);
    }
  }

  // ---- flush partials (plain bf16 stores, no atomics)
  uint16_t* Pb = P + ((size_t)bh * NGRP + blk) * 65 * 256;
  #pragma unroll
  for (int mt = 0; mt < 4; ++mt)
    #pragma unroll
    for (int nt2 = 0; nt2 < 4; ++nt2)
      #pragma unroll
      for (int r = 0; r < 4; ++r)
        Pb[(mt * 16 + quad * 4 + r) * 256 + w * 64 + nt2 * 16 + l] =
            f2b(numacc[mt][nt2][r]);
  #pragma unroll
  for (int jt = 0; jt < 4; ++jt) {
    float v = csum[jt];
    v += __shfl_xor(v, 16); v += __shfl_xor(v, 32);
    if (quad == 0) Pb[64 * 256 + w * 64 + jt * 16 + l] = f2b(v);
  }
}

// ---------------------------------------------------------------------------
// reduce partials -> map_o: MO[b][c=d*4+h][j] = sum_g NUM / sum_g CS
// ---------------------------------------------------------------------------
__global__ __launch_bounds__(256) void reduce_map(
    const uint16_t* __restrict__ P, uint16_t* __restrict__ MO)
{
  const int idx = blockIdx.x * 256 + threadIdx.x;   // 262144 total
  const int bh = idx >> 14;
  const int d = (idx >> 8) & 63;
  const int j = idx & 255;
  const size_t base = (size_t)bh * NGRP * 65 * 256;
  float num = 0.f, cs = 0.f;
  #pragma unroll 6
  for (int g = 0; g < NGRP; ++g) {
    num += b2f(P[base + ((size_t)g * 65 + d) * 256 + j]);
    cs  += b2f(P[base + ((size_t)g * 65 + 64) * 256 + j]);
  }
  const float v = num / cs;
  const int b = bh >> 2, h = bh & 3;
  MO[((size_t)b * 256 + (d * 4 + h)) * 256 + j] = f2b(v);
}

// ---------------------------------------------------------------------------
// map output projection (tiny)
// ---------------------------------------------------------------------------
template<int DT>
DI void map_out_body(const void* __restrict__ Wmo, const uint16_t* __restrict__ MO,
                     void* __restrict__ out)
{
  const int o = blockIdx.x, bb = blockIdx.y, m = threadIdx.x;
  float acc = 0.f;
  #pragma unroll 8
  for (int c = 0; c < 256; ++c)
    acc += ld1<DT>(Wmo, (size_t)o * 256 + c) *
           b2f(MO[((size_t)bb * 256 + c) * 256 + m]);
  const size_t MAP_OFS = (size_t)4 * 256 * NTOK;
  st1<DT>(out, MAP_OFS + ((size_t)bb * 256 + o) * 256 + m, acc);
}
__global__ __launch_bounds__(256) void map_out_k(
    const void* Wmo, const uint16_t* MO, void* out, const int* __restrict__ flag)
{
  if (flag[0]) map_out_body<1>(Wmo, MO, out);
  else         map_out_body<0>(Wmo, MO, out);
}

extern "C" void kernel_launch(void* const* d_in, const int* in_sizes, int n_in,
                              void* d_out, int out_size, void* d_ws, size_t ws_size,
                              hipStream_t stream) {
  (void)in_sizes; (void)n_in; (void)out_size; (void)ws_size;
  const void* feat = d_in[0];
  const void* smap = d_in[1];
  const void* Wfqv = d_in[2];
  const void* Wmqv = d_in[3];
  const void* Wfo  = d_in[4];
  const void* Wmo  = d_in[5];
  char* ws = (char*)d_ws;

  const size_t BIG = (size_t)16 * 64 * NTOK * 2;   // 18,874,368 B
  const size_t SML = (size_t)16 * 256 * 64 * 2;    //    524,288 B
  const size_t FQ_OFF  = 0;                         // FO aliases FQ (token-major)
  const size_t FVT_OFF = FQ_OFF + BIG;
  const size_t MQ_OFF  = FVT_OFF + BIG;
  const size_t MVT_OFF = MQ_OFF + SML;
  const size_t MO_OFF  = MVT_OFF + SML;
  const size_t WQP_OFF = MO_OFF + (size_t)4 * 256 * 256 * 2;
  const size_t WFP_OFF = WQP_OFF + (size_t)512 * 256 * 2;
  const size_t FLAG_OFF = WFP_OFF + (size_t)256 * 256 * 2;

  uint16_t* FQ   = (uint16_t*)(ws + FQ_OFF);
  uint16_t* FVt  = (uint16_t*)(ws + FVT_OFF);
  uint16_t* MQ   = (uint16_t*)(ws + MQ_OFF);
  uint16_t* MVT  = (uint16_t*)(ws + MVT_OFF);
  uint16_t* MO   = (uint16_t*)(ws + MO_OFF);
  uint16_t* WqvP = (uint16_t*)(ws + WQP_OFF);
  uint16_t* WfoP = (uint16_t*)(ws + WFP_OFF);
  int* FLAG   = (int*)(ws + FLAG_OFF);

  // partial buffer P (16 bh x 36 grp x 65 rows x 256 j, bf16 = 19.17 MB)
  // lives in d_out: consumed by reduce_map BEFORE gemm1/map_out overwrite it.
  uint16_t* P = (uint16_t*)d_out;

  detect_dtype<<<dim3(1), dim3(64), 0, stream>>>((const uint32_t*)Wfqv, FLAG);
  prep_w<<<dim3(768), 256, 0, stream>>>(Wfqv, Wfo, WqvP, WfoP, FLAG);
  gemm0_mfma<<<dim3(144, 4), 256, 0, stream>>>(WqvP, feat, FQ, FVt, FLAG);
  map_qv<<<dim3(512, 4), 256, 0, stream>>>(Wmqv, smap, MQ, MVT, FLAG);
  attn_mfma<<<dim3(NGRP, 16), 256, 0, stream>>>(FQ, FVt, MQ, MVT, FQ, P);
  reduce_map<<<dim3(1024), 256, 0, stream>>>(P, MO);
  gemm1_mfma<<<dim3(36, 4, 4), 256, 0, stream>>>(WfoP, FQ, d_out, FLAG);
  map_out_k<<<dim3(256, 4), 256, 0, stream>>>(Wmo, MO, d_out, FLAG);
}